// Round 9
// baseline (113.788 us; speedup 1.0000x reference)
//
#include <hip/hip_runtime.h>
#include <hip/hip_bf16.h>
#include <math.h>

typedef _Float16 half8 __attribute__((ext_vector_type(8)));
typedef _Float16 half4v __attribute__((ext_vector_type(4)));
typedef __fp16 fp16x2 __attribute__((ext_vector_type(2)));
typedef float f32x4 __attribute__((ext_vector_type(4)));
typedef float f32x16 __attribute__((ext_vector_type(16)));

#define D 128
#define SQ 8192
#define SKV 8192
#define BQ 128    // q-rows per block (4 waves x 32)
#define BKV 64
#define LOG2E 1.4426950408889634f
#define DEFER_THR 11.5417f   // 8 * log2(e); P <= 2^11.54 ~ 2981 < f16 max

__device__ __forceinline__ ushort f2bf(float x) {
  union { float f; unsigned u; } v; v.f = x;
  unsigned r = v.u + 0x7fffu + ((v.u >> 16) & 1u);
  return (ushort)(r >> 16);
}
__device__ __forceinline__ float bf2f(ushort h) {
  union { unsigned u; float f; } v; v.u = ((unsigned)h) << 16;
  return v.f;
}
// bf16 pack (for O partials)
__device__ __forceinline__ unsigned cvtpk_bf(float a, float b) {
  unsigned r;
  asm("v_cvt_pk_bf16_f32 %0, %1, %2" : "=v"(r) : "v"(a), "v"(b));
  return r;
}
// f16 pack (HW single-instr, RTZ)
__device__ __forceinline__ unsigned cvtpk_h(float a, float b) {
  union { fp16x2 h; unsigned u; } r;
  r.h = __builtin_amdgcn_cvt_pkrtz(a, b);
  return r.u;
}
__device__ __forceinline__ float fexp2(float x) {
  float r;
  asm("v_exp_f32 %0, %1" : "=v"(r) : "v"(x));
  return r;
}
__device__ __forceinline__ void pl32swap(unsigned& a, unsigned& b) {
  asm("v_permlane32_swap_b32 %0, %1" : "+v"(a), "+v"(b));
}

// q: (D x SQ) f32 -> QT (SQ x D) f16 row-major, scaled by log2e
__global__ void prep_q(const float* __restrict__ src, _Float16* __restrict__ dst) {
  __shared__ float tile[32][33];
  int s0 = blockIdx.x * 32, d0 = blockIdx.y * 32;
  int t = threadIdx.x, g = t >> 5, l = t & 31;
#pragma unroll
  for (int j = 0; j < 4; ++j)
    tile[g * 4 + j][l] = src[(size_t)(d0 + g * 4 + j) * SQ + s0 + l];
  __syncthreads();
#pragma unroll
  for (int j = 0; j < 4; ++j) {
    int sl = g * 4 + j;
    dst[(size_t)(s0 + sl) * D + d0 + l] = (_Float16)(tile[l][sl] * LOG2E);
  }
}

// k: (D x SKV) f32 -> PK packed A-frag order (f16):
// elem = (kvt*8 + dcol/16)*512 + (((dcol>>3)&1)*32 + (srow&31))*8 + (dcol&7)
__global__ void prep_k(const float* __restrict__ src, _Float16* __restrict__ dst) {
  __shared__ float tile[32][33];
  int s0 = blockIdx.x * 32, d0 = blockIdx.y * 32;
  int t = threadIdx.x, g = t >> 5, l = t & 31;
#pragma unroll
  for (int j = 0; j < 4; ++j)
    tile[g * 4 + j][l] = src[(size_t)(d0 + g * 4 + j) * SKV + s0 + l];
  __syncthreads();
#pragma unroll
  for (int j = 0; j < 4; ++j) {
    int srow = s0 + g * 4 + j;
    int dcol = d0 + l;
    size_t elem = (size_t)((srow >> 5) * 8 + (dcol >> 4)) * 512 +
                  (((dcol >> 3) & 1) * 32 + (srow & 31)) * 8 + (dcol & 7);
    dst[elem] = (_Float16)tile[l][g * 4 + j];
  }
}

// v: (D x SKV) f32 -> PV packed A-frag order (f16):
// elem = kvb*8192 + ((drow>>5)*4 + ((kv>>4)&3))*512 + (((kv>>3)&1)*32 + (drow&31))*8 + (kv&7)
__global__ void prep_v(const float* __restrict__ src, _Float16* __restrict__ dst) {
  int i4 = (blockIdx.x * 256 + threadIdx.x) * 4;
  float4 v = *(const float4*)(src + i4);
  int drow = i4 >> 13;          // / SKV
  int kv = i4 & (SKV - 1);
  size_t elem = (size_t)(kv >> 6) * 8192 +
                (size_t)((drow >> 5) * 4 + ((kv >> 4) & 3)) * 512 +
                (((kv >> 3) & 1) * 32 + (drow & 31)) * 8 + (kv & 7);
  half4v o = { (_Float16)v.x, (_Float16)v.y, (_Float16)v.z, (_Float16)v.w };
  *(half4v*)(dst + elem) = o;
}

// Barrier-free flash: no LDS, waves fully independent; K/V read from L1/L2
// as pre-packed contiguous 1KB wave-fragments. Explicit cross-phase prefetch:
//   QK(ka) -> issue va -> softmax -> pack -> issue next ka -> PV(va)
// so every load batch has >=500 cyc of compute before first use.
__global__ __launch_bounds__(256, 2)
void flash_fwd(const _Float16* __restrict__ QT, const _Float16* __restrict__ PK,
               const _Float16* __restrict__ PV,
               ushort* __restrict__ Opart, float* __restrict__ Mst,
               float* __restrict__ Lst, int splitLen) {
  const int tid = threadIdx.x;
  const int w = tid >> 6;
  const int lane = tid & 63;
  const int lc = lane & 31;
  const int hi = lane >> 5;
  const int qb = blockIdx.x;
  const int split = blockIdx.y;
  const int qrow = qb * BQ + w * 32 + lc;

  // Q B-frags (col = q = lc, k-dim = d), pre-scaled by log2e
  half8 qh[8];
#pragma unroll
  for (int ds = 0; ds < 8; ++ds)
    qh[ds] = *(const half8*)(QT + (size_t)qrow * D + ds * 16 + hi * 8);

  f32x16 Ot[4];
#pragma unroll
  for (int dt = 0; dt < 4; ++dt)
#pragma unroll
    for (int e = 0; e < 16; ++e) Ot[dt][e] = 0.f;
  float mrun = -INFINITY, lrun = 0.f;

  const int kvBase = split * splitLen;
  const int nsteps = splitLen / BKV;

  const _Float16* kp = PK + (size_t)kvBase * D + lane * 8;
  const _Float16* vp = PV + (size_t)kvBase * D + lane * 8;

  // ---- prologue: batch-load K tile for step 0 ----
  half8 ka[16];
#pragma unroll
  for (int j = 0; j < 16; ++j) ka[j] = *(const half8*)(kp + j * 512);

  for (int it = 0; it < nsteps; ++it) {
    const bool more = (it + 1 < nsteps);

    // ---- S^T = K Q^T: single f16 term, 2 accumulator chains ----
    f32x16 s0, s1;
#pragma unroll
    for (int e = 0; e < 16; ++e) { s0[e] = 0.f; s1[e] = 0.f; }
    __builtin_amdgcn_s_setprio(1);
#pragma unroll
    for (int ds = 0; ds < 8; ++ds) {
      s0 = __builtin_amdgcn_mfma_f32_32x32x16_f16(ka[ds], qh[ds], s0, 0, 0, 0);
      s1 = __builtin_amdgcn_mfma_f32_32x32x16_f16(ka[8 + ds], qh[ds], s1, 0, 0, 0);
    }
    __builtin_amdgcn_s_setprio(0);

    // ---- issue ALL V loads now: softmax+pack (~700 cyc) covers L2 latency ----
    half8 va[16];
#pragma unroll
    for (int f = 0; f < 16; ++f) va[f] = *(const half8*)(vp + f * 512);

    // ---- in-register online softmax (exp2 domain), tree reductions ----
    float t8[8];
#pragma unroll
    for (int e = 0; e < 8; ++e)
      t8[e] = fmaxf(fmaxf(s0[e], s0[e + 8]), fmaxf(s1[e], s1[e + 8]));
    float mx = fmaxf(fmaxf(fmaxf(t8[0], t8[4]), fmaxf(t8[1], t8[5])),
                     fmaxf(fmaxf(t8[2], t8[6]), fmaxf(t8[3], t8[7])));
    mx = fmaxf(mx, __shfl_xor(mx, 32));

    if (!__all(mx - mrun <= DEFER_THR)) {     // defer-max (T13)
      float mn = fmaxf(mrun, mx);
      float sc = fexp2(mrun - mn);            // first iter: exp2(-inf)=0
      mrun = mn;
      lrun *= sc;
#pragma unroll
      for (int dt = 0; dt < 4; ++dt)
#pragma unroll
        for (int e = 0; e < 16; ++e) Ot[dt][e] *= sc;
    }

#pragma unroll
    for (int e = 0; e < 16; ++e) {
      s0[e] = fexp2(s0[e] - mrun);
      s1[e] = fexp2(s1[e] - mrun);
    }
    float a8[8];
#pragma unroll
    for (int e = 0; e < 8; ++e) a8[e] = (s0[e] + s0[e + 8]) + (s1[e] + s1[e + 8]);
    float lsum = ((a8[0] + a8[4]) + (a8[1] + a8[5])) +
                 ((a8[2] + a8[6]) + (a8[3] + a8[7]));
    lsum += __shfl_xor(lsum, 32);
    lrun += lsum;

    // ---- P -> f16 B-frags in-register (T12: cvt_pkrtz + permlane32_swap) ----
    unsigned pk[8];
    half8 pb[4];
    union { unsigned u[4]; half8 v; } pbu;
#pragma unroll
    for (int j = 0; j < 8; ++j) pk[j] = cvtpk_h(s0[2 * j], s0[2 * j + 1]);
    pl32swap(pk[0], pk[2]); pl32swap(pk[1], pk[3]);
    pl32swap(pk[4], pk[6]); pl32swap(pk[5], pk[7]);
    pbu.u[0] = pk[0]; pbu.u[1] = pk[1]; pbu.u[2] = pk[2]; pbu.u[3] = pk[3]; pb[0] = pbu.v;
    pbu.u[0] = pk[4]; pbu.u[1] = pk[5]; pbu.u[2] = pk[6]; pbu.u[3] = pk[7]; pb[1] = pbu.v;
#pragma unroll
    for (int j = 0; j < 8; ++j) pk[j] = cvtpk_h(s1[2 * j], s1[2 * j + 1]);
    pl32swap(pk[0], pk[2]); pl32swap(pk[1], pk[3]);
    pl32swap(pk[4], pk[6]); pl32swap(pk[5], pk[7]);
    pbu.u[0] = pk[0]; pbu.u[1] = pk[1]; pbu.u[2] = pk[2]; pbu.u[3] = pk[3]; pb[2] = pbu.v;
    pbu.u[0] = pk[4]; pbu.u[1] = pk[5]; pbu.u[2] = pk[6]; pbu.u[3] = pk[7]; pb[3] = pbu.v;

    // ---- prefetch next step's K tile: PV's MFMAs (~1024 cyc) cover latency;
    //      ka is dead after QK, so overwrite in place ----
    if (more) {
      kp += (size_t)BKV * D;
#pragma unroll
      for (int j = 0; j < 16; ++j) ka[j] = *(const half8*)(kp + j * 512);
    }

    // ---- PV: O^T += V^T P^T ----
    __builtin_amdgcn_s_setprio(1);
#pragma unroll
    for (int cc = 0; cc < 4; ++cc) {
      Ot[0] = __builtin_amdgcn_mfma_f32_32x32x16_f16(va[0 * 4 + cc], pb[cc], Ot[0], 0, 0, 0);
      Ot[1] = __builtin_amdgcn_mfma_f32_32x32x16_f16(va[1 * 4 + cc], pb[cc], Ot[1], 0, 0, 0);
      Ot[2] = __builtin_amdgcn_mfma_f32_32x32x16_f16(va[2 * 4 + cc], pb[cc], Ot[2], 0, 0, 0);
      Ot[3] = __builtin_amdgcn_mfma_f32_32x32x16_f16(va[3 * 4 + cc], pb[cc], Ot[3], 0, 0, 0);
    }
    __builtin_amdgcn_s_setprio(0);

    vp += (size_t)BKV * D;
  }

  // ---- epilogue: bf16 partials; d = dt*32 + rg*8 + hi*4 + e ----
  ushort* Op = Opart + (size_t)split * SQ * D + (size_t)qrow * D;
#pragma unroll
  for (int dt = 0; dt < 4; ++dt) {
#pragma unroll
    for (int rg = 0; rg < 4; ++rg) {
      uint2 o2;
      o2.x = cvtpk_bf(Ot[dt][4 * rg + 0], Ot[dt][4 * rg + 1]);
      o2.y = cvtpk_bf(Ot[dt][4 * rg + 2], Ot[dt][4 * rg + 3]);
      *(uint2*)(Op + dt * 32 + rg * 8 + hi * 4) = o2;
    }
  }
  if (hi == 0) {
    Mst[split * SQ + qrow] = mrun;   // log2-domain
    Lst[split * SQ + qrow] = lrun;
  }
}

__global__ void combine(const ushort* __restrict__ Opart, const float* __restrict__ Mst,
                        const float* __restrict__ Lst, float* __restrict__ out, int nsplit) {
  int t4 = (blockIdx.x * 256 + threadIdx.x) * 4;
  int qi = t4 >> 7;
  float M = -INFINITY;
  for (int s = 0; s < nsplit; ++s) M = fmaxf(M, Mst[s * SQ + qi]);
  float n0 = 0.f, n1 = 0.f, n2 = 0.f, n3 = 0.f, den = 0.f;
  for (int s = 0; s < nsplit; ++s) {
    float wgt = fexp2(Mst[s * SQ + qi] - M);
    den += wgt * Lst[s * SQ + qi];
    ushort4 u = *(const ushort4*)(Opart + (size_t)s * SQ * D + t4);
    n0 += wgt * bf2f(u.x); n1 += wgt * bf2f(u.y);
    n2 += wgt * bf2f(u.z); n3 += wgt * bf2f(u.w);
  }
  float inv = 1.0f / den;
  float4 o = { n0 * inv, n1 * inv, n2 * inv, n3 * inv };
  *(float4*)(out + t4) = o;
}

extern "C" void kernel_launch(void* const* d_in, const int* in_sizes, int n_in,
                              void* d_out, int out_size, void* d_ws, size_t ws_size,
                              hipStream_t stream) {
  const float* q = (const float*)d_in[0];
  const float* k = (const float*)d_in[1];
  const float* v = (const float*)d_in[2];
  float* out = (float*)d_out;

  char* ws = (char*)d_ws;
  const size_t mat = (size_t)SQ * D * 2;   // 2 MB per f16 matrix
  _Float16* QT = (_Float16*)(ws);
  _Float16* PK = (_Float16*)(ws + mat);
  _Float16* PV = (_Float16*)(ws + 2 * mat);
  char* rest = ws + 3 * mat;

  const size_t opartSz = (size_t)SQ * D * 2;  // bf16 partials: 2 MB per split
  const size_t statSz  = (size_t)SQ * 4;
  int nsplit = 16;   // grid 64 x 16 = 1024 blocks
  while (nsplit > 1 &&
         3 * mat + (size_t)nsplit * (opartSz + 2 * statSz) > ws_size) nsplit >>= 1;

  ushort* Opart = (ushort*)rest;
  float* Mst = (float*)(rest + (size_t)nsplit * opartSz);
  float* Lst = (float*)(rest + (size_t)nsplit * opartSz + (size_t)nsplit * statSz);

  prep_q<<<dim3(SQ / 32, D / 32), 256, 0, stream>>>(q, QT);
  prep_k<<<dim3(SKV / 32, D / 32), 256, 0, stream>>>(k, PK);
  prep_v<<<(D * SKV) / (256 * 4), 256, 0, stream>>>(v, PV);
  flash_fwd<<<dim3(SQ / BQ, nsplit), 256, 0, stream>>>(QT, PK, PV,
                                                       Opart, Mst, Lst, SKV / nsplit);
  combine<<<(SQ * D) / (256 * 4), 256, 0, stream>>>(Opart, Mst, Lst, out, nsplit);
}

// Round 10
// 98.663 us; speedup vs baseline: 1.1533x; 1.1533x over previous
//
#include <hip/hip_runtime.h>
#include <hip/hip_bf16.h>
#include <math.h>

typedef _Float16 half8 __attribute__((ext_vector_type(8)));
typedef _Float16 half4v __attribute__((ext_vector_type(4)));
typedef __fp16 fp16x2 __attribute__((ext_vector_type(2)));
typedef float f32x4 __attribute__((ext_vector_type(4)));
typedef float f32x16 __attribute__((ext_vector_type(16)));

#define D 128
#define SQ 8192
#define SKV 8192
#define BQ 256    // q-rows per block: 4 waves x 64 (2 C-tiles of 32 per wave)
#define BKV 64
#define LOG2E 1.4426950408889634f
#define DEFER_THR 11.5417f   // 8 * log2(e); P <= 2^11.54 ~ 2981 < f16 max

__device__ __forceinline__ ushort f2bf(float x) {
  union { float f; unsigned u; } v; v.f = x;
  unsigned r = v.u + 0x7fffu + ((v.u >> 16) & 1u);
  return (ushort)(r >> 16);
}
__device__ __forceinline__ float bf2f(ushort h) {
  union { unsigned u; float f; } v; v.u = ((unsigned)h) << 16;
  return v.f;
}
__device__ __forceinline__ unsigned cvtpk_bf(float a, float b) {
  unsigned r;
  asm("v_cvt_pk_bf16_f32 %0, %1, %2" : "=v"(r) : "v"(a), "v"(b));
  return r;
}
__device__ __forceinline__ unsigned cvtpk_h(float a, float b) {
  union { fp16x2 h; unsigned u; } r;
  r.h = __builtin_amdgcn_cvt_pkrtz(a, b);
  return r.u;
}
__device__ __forceinline__ float fexp2(float x) {
  float r;
  asm("v_exp_f32 %0, %1" : "=v"(r) : "v"(x));
  return r;
}
__device__ __forceinline__ void pl32swap(unsigned& a, unsigned& b) {
  asm("v_permlane32_swap_b32 %0, %1" : "+v"(a), "+v"(b));
}

// q: (D x SQ) f32 -> QT (SQ x D) f16 row-major, scaled by log2e
__global__ void prep_q(const float* __restrict__ src, _Float16* __restrict__ dst) {
  __shared__ float tile[32][33];
  int s0 = blockIdx.x * 32, d0 = blockIdx.y * 32;
  int t = threadIdx.x, g = t >> 5, l = t & 31;
#pragma unroll
  for (int j = 0; j < 4; ++j)
    tile[g * 4 + j][l] = src[(size_t)(d0 + g * 4 + j) * SQ + s0 + l];
  __syncthreads();
#pragma unroll
  for (int j = 0; j < 4; ++j) {
    int sl = g * 4 + j;
    dst[(size_t)(s0 + sl) * D + d0 + l] = (_Float16)(tile[l][sl] * LOG2E);
  }
}

// k: (D x SKV) f32 -> PK packed A-frag order (f16)
__global__ void prep_k(const float* __restrict__ src, _Float16* __restrict__ dst) {
  __shared__ float tile[32][33];
  int s0 = blockIdx.x * 32, d0 = blockIdx.y * 32;
  int t = threadIdx.x, g = t >> 5, l = t & 31;
#pragma unroll
  for (int j = 0; j < 4; ++j)
    tile[g * 4 + j][l] = src[(size_t)(d0 + g * 4 + j) * SKV + s0 + l];
  __syncthreads();
#pragma unroll
  for (int j = 0; j < 4; ++j) {
    int srow = s0 + g * 4 + j;
    int dcol = d0 + l;
    size_t elem = (size_t)((srow >> 5) * 8 + (dcol >> 4)) * 512 +
                  (((dcol >> 3) & 1) * 32 + (srow & 31)) * 8 + (dcol & 7);
    dst[elem] = (_Float16)tile[l][g * 4 + j];
  }
}

// v: (D x SKV) f32 -> PV packed A-frag order (f16)
__global__ void prep_v(const float* __restrict__ src, _Float16* __restrict__ dst) {
  int i4 = (blockIdx.x * 256 + threadIdx.x) * 4;
  float4 v = *(const float4*)(src + i4);
  int drow = i4 >> 13;          // / SKV
  int kv = i4 & (SKV - 1);
  size_t elem = (size_t)(kv >> 6) * 8192 +
                (size_t)((drow >> 5) * 4 + ((kv >> 4) & 3)) * 512 +
                (((kv >> 3) & 1) * 32 + (drow & 31)) * 8 + (kv & 7);
  half4v o = { (_Float16)v.x, (_Float16)v.y, (_Float16)v.z, (_Float16)v.w };
  *(half4v*)(dst + elem) = o;
}

// softmax + P-pack for one 32-row tile (s0,s1 = S^T halves; outputs pb[4])
#define SOFTMAX_PACK(s0, s1, mrun, lrun, Ot, pb)                              \
  {                                                                           \
    float t8[8];                                                              \
    _Pragma("unroll")                                                         \
    for (int e = 0; e < 8; ++e)                                               \
      t8[e] = fmaxf(fmaxf(s0[e], s0[e + 8]), fmaxf(s1[e], s1[e + 8]));        \
    float mx = fmaxf(fmaxf(fmaxf(t8[0], t8[4]), fmaxf(t8[1], t8[5])),         \
                     fmaxf(fmaxf(t8[2], t8[6]), fmaxf(t8[3], t8[7])));        \
    mx = fmaxf(mx, __shfl_xor(mx, 32));                                       \
    if (!__all(mx - mrun <= DEFER_THR)) {                                     \
      float mn = fmaxf(mrun, mx);                                             \
      float sc = fexp2(mrun - mn);                                            \
      mrun = mn;                                                              \
      lrun *= sc;                                                             \
      _Pragma("unroll")                                                       \
      for (int dt = 0; dt < 4; ++dt)                                          \
        _Pragma("unroll")                                                     \
        for (int e = 0; e < 16; ++e) Ot[dt][e] *= sc;                         \
    }                                                                         \
    _Pragma("unroll")                                                         \
    for (int e = 0; e < 16; ++e) {                                            \
      s0[e] = fexp2(s0[e] - mrun);                                            \
      s1[e] = fexp2(s1[e] - mrun);                                            \
    }                                                                         \
    float a8[8];                                                              \
    _Pragma("unroll")                                                         \
    for (int e = 0; e < 8; ++e) a8[e] = (s0[e] + s0[e + 8]) + (s1[e] + s1[e + 8]); \
    float lsum = ((a8[0] + a8[4]) + (a8[1] + a8[5])) +                        \
                 ((a8[2] + a8[6]) + (a8[3] + a8[7]));                         \
    lsum += __shfl_xor(lsum, 32);                                             \
    lrun += lsum;                                                             \
    unsigned pk[8];                                                           \
    union { unsigned u[4]; half8 v; } pbu;                                    \
    _Pragma("unroll")                                                         \
    for (int j = 0; j < 8; ++j) pk[j] = cvtpk_h(s0[2 * j], s0[2 * j + 1]);    \
    pl32swap(pk[0], pk[2]); pl32swap(pk[1], pk[3]);                           \
    pl32swap(pk[4], pk[6]); pl32swap(pk[5], pk[7]);                           \
    pbu.u[0] = pk[0]; pbu.u[1] = pk[1]; pbu.u[2] = pk[2]; pbu.u[3] = pk[3];   \
    pb[0] = pbu.v;                                                            \
    pbu.u[0] = pk[4]; pbu.u[1] = pk[5]; pbu.u[2] = pk[6]; pbu.u[3] = pk[7];   \
    pb[1] = pbu.v;                                                            \
    _Pragma("unroll")                                                         \
    for (int j = 0; j < 8; ++j) pk[j] = cvtpk_h(s1[2 * j], s1[2 * j + 1]);    \
    pl32swap(pk[0], pk[2]); pl32swap(pk[1], pk[3]);                           \
    pl32swap(pk[4], pk[6]); pl32swap(pk[5], pk[7]);                           \
    pbu.u[0] = pk[0]; pbu.u[1] = pk[1]; pbu.u[2] = pk[2]; pbu.u[3] = pk[3];   \
    pb[2] = pbu.v;                                                            \
    pbu.u[0] = pk[4]; pbu.u[1] = pk[5]; pbu.u[2] = pk[6]; pbu.u[3] = pk[7];   \
    pb[3] = pbu.v;                                                            \
  }

// Barrier-free flash, fat waves: 64 q-rows (2 C-tiles) per wave, 1 wave/SIMD.
// K/V fragments loaded once per step feed 2x MFMAs (load-pipe pressure halved
// per unit work vs 32-row waves).
__global__ __launch_bounds__(256, 1)
void flash_fwd(const _Float16* __restrict__ QT, const _Float16* __restrict__ PK,
               const _Float16* __restrict__ PV,
               ushort* __restrict__ Opart, float* __restrict__ Mst,
               float* __restrict__ Lst, int splitLen) {
  const int tid = threadIdx.x;
  const int w = tid >> 6;
  const int lane = tid & 63;
  const int lc = lane & 31;
  const int hi = lane >> 5;
  const int qblk = blockIdx.x;
  const int split = blockIdx.y;
  const int qrowA = qblk * BQ + w * 64 + lc;
  const int qrowB = qrowA + 32;

  // Q B-frags for both tiles (col = q, k-dim = d), pre-scaled by log2e
  half8 qfA[8], qfB[8];
#pragma unroll
  for (int ds = 0; ds < 8; ++ds) {
    qfA[ds] = *(const half8*)(QT + (size_t)qrowA * D + ds * 16 + hi * 8);
    qfB[ds] = *(const half8*)(QT + (size_t)qrowB * D + ds * 16 + hi * 8);
  }

  f32x16 OtA[4], OtB[4];
#pragma unroll
  for (int dt = 0; dt < 4; ++dt)
#pragma unroll
    for (int e = 0; e < 16; ++e) { OtA[dt][e] = 0.f; OtB[dt][e] = 0.f; }
  float mrunA = -INFINITY, lrunA = 0.f;
  float mrunB = -INFINITY, lrunB = 0.f;

  const int kvBase = split * splitLen;
  const int nsteps = splitLen / BKV;

  const _Float16* kp = PK + (size_t)kvBase * D + lane * 8;
  const _Float16* vp = PV + (size_t)kvBase * D + lane * 8;

  for (int it = 0; it < nsteps; ++it) {
    // ---- K A-frags: 16 contiguous 1KB wave-loads (used by BOTH q-tiles) ----
    half8 ka[16];
#pragma unroll
    for (int j = 0; j < 16; ++j) ka[j] = *(const half8*)(kp + j * 512);

    // ---- S^T = K Q^T for both tiles: 32 MFMAs off one ka set ----
    f32x16 sA0, sA1, sB0, sB1;
#pragma unroll
    for (int e = 0; e < 16; ++e) { sA0[e] = 0.f; sA1[e] = 0.f; sB0[e] = 0.f; sB1[e] = 0.f; }
    __builtin_amdgcn_s_setprio(1);
#pragma unroll
    for (int ds = 0; ds < 8; ++ds) {
      sA0 = __builtin_amdgcn_mfma_f32_32x32x16_f16(ka[ds], qfA[ds], sA0, 0, 0, 0);
      sA1 = __builtin_amdgcn_mfma_f32_32x32x16_f16(ka[8 + ds], qfA[ds], sA1, 0, 0, 0);
      sB0 = __builtin_amdgcn_mfma_f32_32x32x16_f16(ka[ds], qfB[ds], sB0, 0, 0, 0);
      sB1 = __builtin_amdgcn_mfma_f32_32x32x16_f16(ka[8 + ds], qfB[ds], sB1, 0, 0, 0);
    }
    __builtin_amdgcn_s_setprio(0);

    // ---- V A-frags: softmax (~1400 cyc for 2 tiles) covers L2 latency ----
    half8 va[16];
#pragma unroll
    for (int f = 0; f < 16; ++f) va[f] = *(const half8*)(vp + f * 512);

    // ---- softmax + pack, per tile ----
    half8 pbA[4], pbB[4];
    SOFTMAX_PACK(sA0, sA1, mrunA, lrunA, OtA, pbA);
    SOFTMAX_PACK(sB0, sB1, mrunB, lrunB, OtB, pbB);

    // ---- PV for both tiles off one va set ----
    __builtin_amdgcn_s_setprio(1);
#pragma unroll
    for (int cc = 0; cc < 4; ++cc) {
#pragma unroll
      for (int dt = 0; dt < 4; ++dt) {
        OtA[dt] = __builtin_amdgcn_mfma_f32_32x32x16_f16(va[dt * 4 + cc], pbA[cc], OtA[dt], 0, 0, 0);
        OtB[dt] = __builtin_amdgcn_mfma_f32_32x32x16_f16(va[dt * 4 + cc], pbB[cc], OtB[dt], 0, 0, 0);
      }
    }
    __builtin_amdgcn_s_setprio(0);

    kp += (size_t)BKV * D;
    vp += (size_t)BKV * D;
  }

  // ---- epilogue: bf16 partials; d = dt*32 + rg*8 + hi*4 + e ----
  ushort* OpA = Opart + (size_t)split * SQ * D + (size_t)qrowA * D;
  ushort* OpB = Opart + (size_t)split * SQ * D + (size_t)qrowB * D;
#pragma unroll
  for (int dt = 0; dt < 4; ++dt) {
#pragma unroll
    for (int rg = 0; rg < 4; ++rg) {
      uint2 oA, oB;
      oA.x = cvtpk_bf(OtA[dt][4 * rg + 0], OtA[dt][4 * rg + 1]);
      oA.y = cvtpk_bf(OtA[dt][4 * rg + 2], OtA[dt][4 * rg + 3]);
      oB.x = cvtpk_bf(OtB[dt][4 * rg + 0], OtB[dt][4 * rg + 1]);
      oB.y = cvtpk_bf(OtB[dt][4 * rg + 2], OtB[dt][4 * rg + 3]);
      *(uint2*)(OpA + dt * 32 + rg * 8 + hi * 4) = oA;
      *(uint2*)(OpB + dt * 32 + rg * 8 + hi * 4) = oB;
    }
  }
  if (hi == 0) {
    Mst[split * SQ + qrowA] = mrunA;   // log2-domain
    Lst[split * SQ + qrowA] = lrunA;
    Mst[split * SQ + qrowB] = mrunB;
    Lst[split * SQ + qrowB] = lrunB;
  }
}

__global__ void combine(const ushort* __restrict__ Opart, const float* __restrict__ Mst,
                        const float* __restrict__ Lst, float* __restrict__ out, int nsplit) {
  int t4 = (blockIdx.x * 256 + threadIdx.x) * 4;
  int qi = t4 >> 7;
  float M = -INFINITY;
  for (int s = 0; s < nsplit; ++s) M = fmaxf(M, Mst[s * SQ + qi]);
  float n0 = 0.f, n1 = 0.f, n2 = 0.f, n3 = 0.f, den = 0.f;
  for (int s = 0; s < nsplit; ++s) {
    float wgt = fexp2(Mst[s * SQ + qi] - M);
    den += wgt * Lst[s * SQ + qi];
    ushort4 u = *(const ushort4*)(Opart + (size_t)s * SQ * D + t4);
    n0 += wgt * bf2f(u.x); n1 += wgt * bf2f(u.y);
    n2 += wgt * bf2f(u.z); n3 += wgt * bf2f(u.w);
  }
  float inv = 1.0f / den;
  float4 o = { n0 * inv, n1 * inv, n2 * inv, n3 * inv };
  *(float4*)(out + t4) = o;
}

extern "C" void kernel_launch(void* const* d_in, const int* in_sizes, int n_in,
                              void* d_out, int out_size, void* d_ws, size_t ws_size,
                              hipStream_t stream) {
  const float* q = (const float*)d_in[0];
  const float* k = (const float*)d_in[1];
  const float* v = (const float*)d_in[2];
  float* out = (float*)d_out;

  char* ws = (char*)d_ws;
  const size_t mat = (size_t)SQ * D * 2;   // 2 MB per f16 matrix
  _Float16* QT = (_Float16*)(ws);
  _Float16* PK = (_Float16*)(ws + mat);
  _Float16* PV = (_Float16*)(ws + 2 * mat);
  char* rest = ws + 3 * mat;

  const size_t opartSz = (size_t)SQ * D * 2;  // bf16 partials: 2 MB per split
  const size_t statSz  = (size_t)SQ * 4;
  int nsplit = 16;   // grid 32 x 16 = 512 blocks = 2 sequential blocks/CU
  while (nsplit > 1 &&
         3 * mat + (size_t)nsplit * (opartSz + 2 * statSz) > ws_size) nsplit >>= 1;

  ushort* Opart = (ushort*)rest;
  float* Mst = (float*)(rest + (size_t)nsplit * opartSz);
  float* Lst = (float*)(rest + (size_t)nsplit * opartSz + (size_t)nsplit * statSz);

  prep_q<<<dim3(SQ / 32, D / 32), 256, 0, stream>>>(q, QT);
  prep_k<<<dim3(SKV / 32, D / 32), 256, 0, stream>>>(k, PK);
  prep_v<<<(D * SKV) / (256 * 4), 256, 0, stream>>>(v, PV);
  flash_fwd<<<dim3(SQ / BQ, nsplit), 256, 0, stream>>>(QT, PK, PV,
                                                       Opart, Mst, Lst, SKV / nsplit);
  combine<<<(SQ * D) / (256 * 4), 256, 0, stream>>>(Opart, Mst, Lst, out, nsplit);
}

// Round 11
// 65.453 us; speedup vs baseline: 1.7385x; 1.5074x over previous
//
#include <hip/hip_runtime.h>
#include <hip/hip_bf16.h>
#include <math.h>

typedef _Float16 half8 __attribute__((ext_vector_type(8)));
typedef _Float16 half4v __attribute__((ext_vector_type(4)));
typedef __fp16 fp16x2 __attribute__((ext_vector_type(2)));
typedef float f32x4 __attribute__((ext_vector_type(4)));
typedef float f32x16 __attribute__((ext_vector_type(16)));

#define D 128
#define SQ 8192
#define SKV 8192
#define BQ 128    // q-rows per block (4 waves x 32)
#define BKV 64
#define LOG2E 1.4426950408889634f
#define DEFER_THR 11.5417f   // 8 * log2(e); P <= 2^11.54 ~ 2981 < f16 max

__device__ __forceinline__ ushort f2bf(float x) {
  union { float f; unsigned u; } v; v.f = x;
  unsigned r = v.u + 0x7fffu + ((v.u >> 16) & 1u);
  return (ushort)(r >> 16);
}
__device__ __forceinline__ float bf2f(ushort h) {
  union { unsigned u; float f; } v; v.u = ((unsigned)h) << 16;
  return v.f;
}
__device__ __forceinline__ unsigned cvtpk_bf(float a, float b) {
  unsigned r;
  asm("v_cvt_pk_bf16_f32 %0, %1, %2" : "=v"(r) : "v"(a), "v"(b));
  return r;
}
__device__ __forceinline__ unsigned cvtpk_h(float a, float b) {
  union { fp16x2 h; unsigned u; } r;
  r.h = __builtin_amdgcn_cvt_pkrtz(a, b);
  return r.u;
}
__device__ __forceinline__ float fexp2(float x) {
  float r;
  asm("v_exp_f32 %0, %1" : "=v"(r) : "v"(x));
  return r;
}
__device__ __forceinline__ void pl32swap(unsigned& a, unsigned& b) {
  asm("v_permlane32_swap_b32 %0, %1" : "+v"(a), "+v"(b));
}

// q: (D x SQ) f32 -> QT (SQ x D) f16 row-major, scaled by log2e
__global__ void prep_q(const float* __restrict__ src, _Float16* __restrict__ dst) {
  __shared__ float tile[32][33];
  int s0 = blockIdx.x * 32, d0 = blockIdx.y * 32;
  int t = threadIdx.x, g = t >> 5, l = t & 31;
#pragma unroll
  for (int j = 0; j < 4; ++j)
    tile[g * 4 + j][l] = src[(size_t)(d0 + g * 4 + j) * SQ + s0 + l];
  __syncthreads();
#pragma unroll
  for (int j = 0; j < 4; ++j) {
    int sl = g * 4 + j;
    dst[(size_t)(s0 + sl) * D + d0 + l] = (_Float16)(tile[l][sl] * LOG2E);
  }
}

// k: (D x SKV) f32 -> PK packed A-frag order (f16):
// elem = (kvt*8 + dcol/16)*512 + (((dcol>>3)&1)*32 + (srow&31))*8 + (dcol&7)
__global__ void prep_k(const float* __restrict__ src, _Float16* __restrict__ dst) {
  __shared__ float tile[32][33];
  int s0 = blockIdx.x * 32, d0 = blockIdx.y * 32;
  int t = threadIdx.x, g = t >> 5, l = t & 31;
#pragma unroll
  for (int j = 0; j < 4; ++j)
    tile[g * 4 + j][l] = src[(size_t)(d0 + g * 4 + j) * SKV + s0 + l];
  __syncthreads();
#pragma unroll
  for (int j = 0; j < 4; ++j) {
    int srow = s0 + g * 4 + j;
    int dcol = d0 + l;
    size_t elem = (size_t)((srow >> 5) * 8 + (dcol >> 4)) * 512 +
                  (((dcol >> 3) & 1) * 32 + (srow & 31)) * 8 + (dcol & 7);
    dst[elem] = (_Float16)tile[l][g * 4 + j];
  }
}

// v: (D x SKV) f32 -> PV packed A-frag order (f16):
// elem = kvb*8192 + ((drow>>5)*4 + ((kv>>4)&3))*512 + (((kv>>3)&1)*32 + (drow&31))*8 + (kv&7)
__global__ void prep_v(const float* __restrict__ src, _Float16* __restrict__ dst) {
  int i4 = (blockIdx.x * 256 + threadIdx.x) * 4;
  float4 v = *(const float4*)(src + i4);
  int drow = i4 >> 13;          // / SKV
  int kv = i4 & (SKV - 1);
  size_t elem = (size_t)(kv >> 6) * 8192 +
                (size_t)((drow >> 5) * 4 + ((kv >> 4) & 3)) * 512 +
                (((kv >> 3) & 1) * 32 + (drow & 31)) * 8 + (kv & 7);
  half4v o = { (_Float16)v.x, (_Float16)v.y, (_Float16)v.z, (_Float16)v.w };
  *(half4v*)(dst + elem) = o;
}

// Flash with LDS-multicast K/V: unique bytes flow through the vector-load pipe
// ONCE per block-step (global_load_lds, linear dest = packed layout), waves
// read fragments via the separate LDS pipe (lane-linear ds_read_b128,
// conflict-free). Double-buffered, one barrier per step, stage issued early.
__global__ __launch_bounds__(256, 2)
void flash_fwd(const _Float16* __restrict__ QT, const _Float16* __restrict__ PK,
               const _Float16* __restrict__ PV,
               ushort* __restrict__ Opart, float* __restrict__ Mst,
               float* __restrict__ Lst, int splitLen) {
  __shared__ _Float16 Kl[2][BKV * D];   // 16 KB per buffer
  __shared__ _Float16 Vl[2][BKV * D];

  const int tid = threadIdx.x;
  const int w = tid >> 6;
  const int lane = tid & 63;
  const int lc = lane & 31;
  const int hi = lane >> 5;
  const int qb = blockIdx.x;
  const int split = blockIdx.y;
  const int qrow = qb * BQ + w * 32 + lc;

  // Q B-frags (col = q = lc, k-dim = d), pre-scaled by log2e
  half8 qh[8];
#pragma unroll
  for (int ds = 0; ds < 8; ++ds)
    qh[ds] = *(const half8*)(QT + (size_t)qrow * D + ds * 16 + hi * 8);

  f32x16 Ot[4];
#pragma unroll
  for (int dt = 0; dt < 4; ++dt)
#pragma unroll
    for (int e = 0; e < 16; ++e) Ot[dt][e] = 0.f;
  float mrun = -INFINITY, lrun = 0.f;

  const int kvBase = split * splitLen;
  const int nsteps = splitLen / BKV;

  // ---- staging: K+V tile = 32 x 1KB chunks; wave w stages chunks w*8..w*8+7.
  // Packed source is linear; LDS dest = uniform base + lane*16 (linear) ----
#define STAGE(NB, KV0)                                                        \
  {                                                                           \
    _Pragma("unroll")                                                         \
    for (int j = 0; j < 8; ++j) {                                             \
      int cblk = w * 8 + j;                                                   \
      int cc = cblk & 15;                                                     \
      const _Float16* gp = ((cblk < 16) ? PK : PV) +                          \
                           (size_t)(KV0) * D + cc * 512 + lane * 8;           \
      _Float16* lp = ((cblk < 16) ? &Kl[NB][0] : &Vl[NB][0]) + cc * 512;      \
      __builtin_amdgcn_global_load_lds(                                       \
          (const __attribute__((address_space(1))) unsigned*)gp,              \
          (__attribute__((address_space(3))) unsigned*)lp, 16, 0, 0);         \
    }                                                                         \
  }

  STAGE(0, kvBase);
  __syncthreads();
  int cur = 0;

  for (int it = 0; it < nsteps; ++it) {
    const int kv0 = kvBase + it * BKV;
    const bool more = (it + 1 < nsteps);
    if (more) STAGE(cur ^ 1, kv0 + BKV);   // in flight across the whole step

    const _Float16* kb = &Kl[cur][0] + lane * 8;
    const _Float16* vb = &Vl[cur][0] + lane * 8;

    // ---- K frags from LDS + QK MFMAs ----
    half8 ka[16];
#pragma unroll
    for (int j = 0; j < 16; ++j) ka[j] = *(const half8*)(kb + j * 512);

    f32x16 s0, s1;
#pragma unroll
    for (int e = 0; e < 16; ++e) { s0[e] = 0.f; s1[e] = 0.f; }
    __builtin_amdgcn_s_setprio(1);
#pragma unroll
    for (int ds = 0; ds < 8; ++ds) {
      s0 = __builtin_amdgcn_mfma_f32_32x32x16_f16(ka[ds], qh[ds], s0, 0, 0, 0);
      s1 = __builtin_amdgcn_mfma_f32_32x32x16_f16(ka[8 + ds], qh[ds], s1, 0, 0, 0);
    }
    __builtin_amdgcn_s_setprio(0);

    // ---- V frags issued now; lgkm latency hides under softmax ----
    half8 va[16];
#pragma unroll
    for (int f = 0; f < 16; ++f) va[f] = *(const half8*)(vb + f * 512);

    // ---- in-register online softmax (exp2 domain), tree reductions ----
    float t8[8];
#pragma unroll
    for (int e = 0; e < 8; ++e)
      t8[e] = fmaxf(fmaxf(s0[e], s0[e + 8]), fmaxf(s1[e], s1[e + 8]));
    float mx = fmaxf(fmaxf(fmaxf(t8[0], t8[4]), fmaxf(t8[1], t8[5])),
                     fmaxf(fmaxf(t8[2], t8[6]), fmaxf(t8[3], t8[7])));
    mx = fmaxf(mx, __shfl_xor(mx, 32));

    if (!__all(mx - mrun <= DEFER_THR)) {     // defer-max (T13)
      float mn = fmaxf(mrun, mx);
      float sc = fexp2(mrun - mn);            // first iter: exp2(-inf)=0
      mrun = mn;
      lrun *= sc;
#pragma unroll
      for (int dt = 0; dt < 4; ++dt)
#pragma unroll
        for (int e = 0; e < 16; ++e) Ot[dt][e] *= sc;
    }

#pragma unroll
    for (int e = 0; e < 16; ++e) {
      s0[e] = fexp2(s0[e] - mrun);
      s1[e] = fexp2(s1[e] - mrun);
    }
    float a8[8];
#pragma unroll
    for (int e = 0; e < 8; ++e) a8[e] = (s0[e] + s0[e + 8]) + (s1[e] + s1[e + 8]);
    float lsum = ((a8[0] + a8[4]) + (a8[1] + a8[5])) +
                 ((a8[2] + a8[6]) + (a8[3] + a8[7]));
    lsum += __shfl_xor(lsum, 32);
    lrun += lsum;

    // ---- P -> f16 B-frags in-register (T12: cvt_pkrtz + permlane32_swap) ----
    unsigned pk[8];
    half8 pb[4];
    union { unsigned u[4]; half8 v; } pbu;
#pragma unroll
    for (int j = 0; j < 8; ++j) pk[j] = cvtpk_h(s0[2 * j], s0[2 * j + 1]);
    pl32swap(pk[0], pk[2]); pl32swap(pk[1], pk[3]);
    pl32swap(pk[4], pk[6]); pl32swap(pk[5], pk[7]);
    pbu.u[0] = pk[0]; pbu.u[1] = pk[1]; pbu.u[2] = pk[2]; pbu.u[3] = pk[3]; pb[0] = pbu.v;
    pbu.u[0] = pk[4]; pbu.u[1] = pk[5]; pbu.u[2] = pk[6]; pbu.u[3] = pk[7]; pb[1] = pbu.v;
#pragma unroll
    for (int j = 0; j < 8; ++j) pk[j] = cvtpk_h(s1[2 * j], s1[2 * j + 1]);
    pl32swap(pk[0], pk[2]); pl32swap(pk[1], pk[3]);
    pl32swap(pk[4], pk[6]); pl32swap(pk[5], pk[7]);
    pbu.u[0] = pk[0]; pbu.u[1] = pk[1]; pbu.u[2] = pk[2]; pbu.u[3] = pk[3]; pb[2] = pbu.v;
    pbu.u[0] = pk[4]; pbu.u[1] = pk[5]; pbu.u[2] = pk[6]; pbu.u[3] = pk[7]; pb[3] = pbu.v;

    // ---- PV: O^T += V^T P^T ----
    __builtin_amdgcn_s_setprio(1);
#pragma unroll
    for (int cc = 0; cc < 4; ++cc) {
      Ot[0] = __builtin_amdgcn_mfma_f32_32x32x16_f16(va[0 * 4 + cc], pb[cc], Ot[0], 0, 0, 0);
      Ot[1] = __builtin_amdgcn_mfma_f32_32x32x16_f16(va[1 * 4 + cc], pb[cc], Ot[1], 0, 0, 0);
      Ot[2] = __builtin_amdgcn_mfma_f32_32x32x16_f16(va[2 * 4 + cc], pb[cc], Ot[2], 0, 0, 0);
      Ot[3] = __builtin_amdgcn_mfma_f32_32x32x16_f16(va[3 * 4 + cc], pb[cc], Ot[3], 0, 0, 0);
    }
    __builtin_amdgcn_s_setprio(0);

    __syncthreads();   // staged tile landed; all reads of cur done -> safe swap
    cur ^= 1;
  }

  // ---- epilogue: bf16 partials; d = dt*32 + rg*8 + hi*4 + e ----
  ushort* Op = Opart + (size_t)split * SQ * D + (size_t)qrow * D;
#pragma unroll
  for (int dt = 0; dt < 4; ++dt) {
#pragma unroll
    for (int rg = 0; rg < 4; ++rg) {
      uint2 o2;
      o2.x = cvtpk_bf(Ot[dt][4 * rg + 0], Ot[dt][4 * rg + 1]);
      o2.y = cvtpk_bf(Ot[dt][4 * rg + 2], Ot[dt][4 * rg + 3]);
      *(uint2*)(Op + dt * 32 + rg * 8 + hi * 4) = o2;
    }
  }
  if (hi == 0) {
    Mst[split * SQ + qrow] = mrun;   // log2-domain
    Lst[split * SQ + qrow] = lrun;
  }
}

__global__ void combine(const ushort* __restrict__ Opart, const float* __restrict__ Mst,
                        const float* __restrict__ Lst, float* __restrict__ out, int nsplit) {
  int t4 = (blockIdx.x * 256 + threadIdx.x) * 4;
  int qi = t4 >> 7;
  float M = -INFINITY;
  for (int s = 0; s < nsplit; ++s) M = fmaxf(M, Mst[s * SQ + qi]);
  float n0 = 0.f, n1 = 0.f, n2 = 0.f, n3 = 0.f, den = 0.f;
  for (int s = 0; s < nsplit; ++s) {
    float wgt = fexp2(Mst[s * SQ + qi] - M);
    den += wgt * Lst[s * SQ + qi];
    ushort4 u = *(const ushort4*)(Opart + (size_t)s * SQ * D + t4);
    n0 += wgt * bf2f(u.x); n1 += wgt * bf2f(u.y);
    n2 += wgt * bf2f(u.z); n3 += wgt * bf2f(u.w);
  }
  float inv = 1.0f / den;
  float4 o = { n0 * inv, n1 * inv, n2 * inv, n3 * inv };
  *(float4*)(out + t4) = o;
}

extern "C" void kernel_launch(void* const* d_in, const int* in_sizes, int n_in,
                              void* d_out, int out_size, void* d_ws, size_t ws_size,
                              hipStream_t stream) {
  const float* q = (const float*)d_in[0];
  const float* k = (const float*)d_in[1];
  const float* v = (const float*)d_in[2];
  float* out = (float*)d_out;

  char* ws = (char*)d_ws;
  const size_t mat = (size_t)SQ * D * 2;   // 2 MB per f16 matrix
  _Float16* QT = (_Float16*)(ws);
  _Float16* PK = (_Float16*)(ws + mat);
  _Float16* PV = (_Float16*)(ws + 2 * mat);
  char* rest = ws + 3 * mat;

  const size_t opartSz = (size_t)SQ * D * 2;  // bf16 partials: 2 MB per split
  const size_t statSz  = (size_t)SQ * 4;
  int nsplit = 8;    // grid 64 x 8 = 512 blocks = 2/CU resident, single pass
  while (nsplit > 1 &&
         3 * mat + (size_t)nsplit * (opartSz + 2 * statSz) > ws_size) nsplit >>= 1;

  ushort* Opart = (ushort*)rest;
  float* Mst = (float*)(rest + (size_t)nsplit * opartSz);
  float* Lst = (float*)(rest + (size_t)nsplit * opartSz + (size_t)nsplit * statSz);

  prep_q<<<dim3(SQ / 32, D / 32), 256, 0, stream>>>(q, QT);
  prep_k<<<dim3(SKV / 32, D / 32), 256, 0, stream>>>(k, PK);
  prep_v<<<(D * SKV) / (256 * 4), 256, 0, stream>>>(v, PV);
  flash_fwd<<<dim3(SQ / BQ, nsplit), 256, 0, stream>>>(QT, PK, PV,
                                                       Opart, Mst, Lst, SKV / nsplit);
  combine<<<(SQ * D) / (256 * 4), 256, 0, stream>>>(Opart, Mst, Lst, out, nsplit);
}